// Round 13
// baseline (40832.791 us; speedup 1.0000x reference)
//
#include <hip/hip_runtime.h>
#include <hip/hip_cooperative_groups.h>

namespace cg = cooperative_groups;

#define Bb   256   // batch
#define Tt   512   // time steps
#define INx  19    // input features
#define Hh   512   // hidden
#define NWG  256   // (unit-group 0..127 of 4 units) x (batch-half 0..1 of 128)
#define NTHR 512   // 8 waves = su(0..3) x kq(0..1); lane = bg 0..63 -> 2 batches

typedef unsigned int u32;
typedef unsigned long long u64;

__device__ __forceinline__ float sigf(float x) { return 1.0f / (1.0f + __expf(-x)); }
__device__ __forceinline__ float tanhfast(float x) {
    float e = __expf(2.0f * x);
    return 1.0f - 2.0f / (e + 1.0f);
}

union pcast { u64 u; float2 f; };
// h stores: agent-scope -> LLC-visible once vmcnt drains (r7/r9-proven)
__device__ __forceinline__ void gstore2(float2* p, float2 v) {
    pcast c; c.f = v;
    __hip_atomic_store((u64*)p, c.u, __ATOMIC_RELAXED, __HIP_MEMORY_SCOPE_AGENT);
}

// r9's exact barrier: drain, release flag, poll 256 flags, acquire fence.
__device__ __forceinline__ void gbar(u32* flags, int wgid, int tid, u32 phase) {
    __syncthreads();
    if (tid == 0)
        __hip_atomic_store(&flags[wgid], phase, __ATOMIC_RELEASE, __HIP_MEMORY_SCOPE_AGENT);
    if (tid < NWG) {
        const u32* fp = &flags[tid];
        while (__hip_atomic_load(fp, __ATOMIC_RELAXED, __HIP_MEMORY_SCOPE_AGENT) < phase)
            __builtin_amdgcn_s_sleep(2);
    }
    __syncthreads();
    __builtin_amdgcn_fence(__ATOMIC_ACQUIRE, "agent");   // L1/L2 inv -> fresh h
}

// load chunk c: 4 consecutive k's, ONE float4 each = (h1,h2) pairs of the
// lane's 2 adjacent batches.
__device__ __forceinline__ void ldc(const float4* __restrict__ hp, int c,
                                    float4 (&H)[4]) {
    #pragma unroll
    for (int kk = 0; kk < 4; ++kk)
        H[kk] = hp[(size_t)(c * 4 + kk) * 128];
}

// 96 FMA: (4 a1-rows + 8 a2-rows merged) x 4 k x 2 batches.
// Weight pointers WAVE-UNIFORM -> s_load, SGPR broadcast operands.
// H[kk] = (h1_b0, h2_b0, h1_b1, h2_b1) at k.
__device__ __forceinline__ void fmac(const float4 (&H)[4],
                                     const float* const (&wb1)[4],
                                     const float* const (&wb2)[4],
                                     const float* const (&wb3)[4], int k4,
                                     float (&a1)[4][2], float (&a2)[4][2]) {
    #pragma unroll
    for (int g = 0; g < 4; ++g) {
        const float4 w1 = *reinterpret_cast<const float4*>(wb1[g] + k4);
        const float4 w2 = *reinterpret_cast<const float4*>(wb2[g] + k4);
        const float4 w3 = *reinterpret_cast<const float4*>(wb3[g] + k4);
        a1[g][0] += H[0].x*w1.x + H[1].x*w1.y + H[2].x*w1.z + H[3].x*w1.w;
        a1[g][1] += H[0].z*w1.x + H[1].z*w1.y + H[2].z*w1.z + H[3].z*w1.w;
        a2[g][0] += H[0].x*w2.x + H[1].x*w2.y + H[2].x*w2.z + H[3].x*w2.w
                  + H[0].y*w3.x + H[1].y*w3.y + H[2].y*w3.z + H[3].y*w3.w;
        a2[g][1] += H[0].z*w2.x + H[1].z*w2.y + H[2].z*w2.z + H[3].z*w2.w
                  + H[0].w*w3.x + H[1].w*w3.y + H[2].w*w3.z + H[3].w*w3.w;
    }
}

__global__ void __launch_bounds__(NTHR, 2)
lstm_fused(const float* __restrict__ input,
           const float* __restrict__ l1_Wx, const float* __restrict__ l1_bx,
           const float* __restrict__ l1_Wh, const float* __restrict__ l1_bh,
           const float* __restrict__ l2_Wx, const float* __restrict__ l2_bx,
           const float* __restrict__ l2_Wh, const float* __restrict__ l2_bh,
           const float* __restrict__ fc1_W, const float* __restrict__ fc1_b,
           const float* __restrict__ fc2_W, const float* __restrict__ fc2_b,
           const float* __restrict__ fc3_W, const float* __restrict__ fc3_b,
           float* __restrict__ out, float* __restrict__ ws)
{
    __shared__ float part[4 * 2 * 8 * 128];   // [su][kq][8 rows][128 b] = 32 KB
    __shared__ float wx1l[16 * 20];           // 4 units x 4 gates, pad 20
    __shared__ float fcb[Hh + 256 + 128];     // FC head scratch

    cg::grid_group grid = cg::this_grid();
    const int wgid = blockIdx.x;
    const int ug = wgid >> 1;        // unit-group
    const int bs = wgid & 1;         // batch-half
    const int jb = ug * 4;           // first owned unit
    const int tid = threadIdx.x;

    // sweep role: wave (su 0..3, kq 0..1); lane bg -> batches bs*128+2bg, +1
    const int wid = __builtin_amdgcn_readfirstlane(tid >> 6);
    const int su = wid & 3;
    const int kq = wid >> 2;
    const int bg = tid & 63;
    const int bl = bg * 2;           // local batch (0..126 even)
    // finish role: thread (fu 0..3, fb 0..127) -> unit jb+fu, batch bs*128+fb
    const int fu = tid >> 7;
    const int fb = tid & 127;
    const int bx = bs * 128 + fb;
    const int j2 = jb + fu;

    float2* PA = (float2*)ws;        // P[j][b] = (h1[t], h2[t-1])
    float2* PB = PA + (size_t)Hh * Bb;
    u32* flags = (u32*)(PB + (size_t)Hh * Bb);

    if (tid == 0)
        __hip_atomic_store(&flags[wgid], 0u, __ATOMIC_RELAXED, __HIP_MEMORY_SCOPE_AGENT);
    grid.sync();   // fences flag resets; the only runtime cg sync

    // ---- wave-uniform scalar weight row bases (s_load path) ----
    const float* wb1[4]; const float* wb2[4]; const float* wb3[4];
    {
        const int j = jb + su;
        #pragma unroll
        for (int g = 0; g < 4; ++g) {
            const size_t off = (size_t)(g * Hh + j) * Hh + kq * 256;
            wb1[g] = l1_Wh + off;
            wb2[g] = l2_Wx + off;
            wb3[g] = l2_Wh + off;
        }
    }

    // ---- stage tiny l1_Wx + biases (finish role) ----
    if (tid < 16 * INx) {
        const int r = tid / INx, i = tid - r * INx;
        const int u = r >> 2, g = r & 3;
        wx1l[r * 20 + i] = l1_Wx[(size_t)(g * Hh + jb + u) * INx + i];
    }
    float b1r[4], b2r[4];
    #pragma unroll
    for (int g = 0; g < 4; ++g) {
        const int row = g * Hh + j2;
        b1r[g] = l1_bx[row] + l1_bh[row];
        b2r[g] = l2_bx[row] + l2_bh[row];
    }
    __syncthreads();

    // ---- prologue: P = (h1[0], h2[-1]=0), finish role ----
    float c1 = 0.f, c2 = 0.f;
    {
        const float* xr = input + (size_t)bx * Tt * INx;
        float s[4];
        #pragma unroll
        for (int g = 0; g < 4; ++g) {
            float acc = b1r[g];
            #pragma unroll
            for (int i = 0; i < INx; ++i) acc += xr[i] * wx1l[(fu * 4 + g) * 20 + i];
            s[g] = acc;
        }
        c1 = sigf(s[0]) * tanhfast(s[2]);
        gstore2(&PA[(size_t)j2 * Bb + bx], make_float2(sigf(s[3]) * tanhfast(c1), 0.f));
    }
    gbar(flags, wgid, tid, 1u);

    const float2* Pc = PA; float2* Pn = PB;

    for (int t = 0; t < Tt; ++t) {
        const bool doL1 = (t < Tt - 1);

        float a1[4][2], a2[4][2];
        #pragma unroll
        for (int g = 0; g < 4; ++g) {
            a1[g][0] = 0.f; a1[g][1] = 0.f;
            a2[g][0] = 0.f; a2[g][1] = 0.f;
        }

        // lane float4 base: f4 idx = k*128 + b/2; k = kq*256 + ...
        const float4* hp = (const float4*)Pc + (size_t)(kq * 256) * 128 + (bs * 64 + bg);

        // r9-proven depth-2 pipeline over 64 chunks of 4 k's
        float4 B0[4], B1[4];
        ldc(hp, 0, B0);
        ldc(hp, 1, B1);
        #pragma unroll 1
        for (int c = 0; c < 60; c += 2) {
            fmac(B0, wb1, wb2, wb3, (c + 0) * 4, a1, a2); ldc(hp, c + 2, B0);
            fmac(B1, wb1, wb2, wb3, (c + 1) * 4, a1, a2); ldc(hp, c + 3, B1);
        }
        fmac(B0, wb1, wb2, wb3, 240, a1, a2); ldc(hp, 62, B0);
        fmac(B1, wb1, wb2, wb3, 244, a1, a2); ldc(hp, 63, B1);
        fmac(B0, wb1, wb2, wb3, 248, a1, a2);
        fmac(B1, wb1, wb2, wb3, 252, a1, a2);

        // ---- K-partial exchange: [su][kq][8 rows][128 b], float2 writes ----
        {
            float* pw = part + (size_t)((su * 2 + kq) * 8) * 128 + bl;
            #pragma unroll
            for (int g = 0; g < 4; ++g) {
                *reinterpret_cast<float2*>(pw + (0 + g) * 128) = make_float2(a1[g][0], a1[g][1]);
                *reinterpret_cast<float2*>(pw + (4 + g) * 128) = make_float2(a2[g][0], a2[g][1]);
            }
        }

        // x[t+1] prefetch (finish role; issued before the sync)
        float xv[INx];
        if (doL1) {
            const float* xr = input + ((size_t)bx * Tt + t + 1) * INx;
            #pragma unroll
            for (int i = 0; i < INx; ++i) xv[i] = xr[i];
        }
        __syncthreads();

        // ---- finish: unit j2, batch bx; reduce the 2 kq rowsets ----
        {
            const float* p0 = part + (size_t)((fu * 2 + 0) * 8) * 128 + fb;
            const float* p1 = part + (size_t)((fu * 2 + 1) * 8) * 128 + fb;
            float s1[4], s2[4];
            #pragma unroll
            for (int g = 0; g < 4; ++g) {
                s1[g] = p0[(0 + g) * 128] + p1[(0 + g) * 128] + b1r[g];
                s2[g] = p0[(4 + g) * 128] + p1[(4 + g) * 128] + b2r[g];
            }
            float h1v = 0.f;
            if (doL1) {
                #pragma unroll
                for (int g = 0; g < 4; ++g) {
                    float acc = s1[g];
                    #pragma unroll
                    for (int i = 0; i < INx; ++i) acc += xv[i] * wx1l[(fu * 4 + g) * 20 + i];
                    s1[g] = acc;
                }
                const float ig = sigf(s1[0]), fg = sigf(s1[1]);
                const float gg = tanhfast(s1[2]), og = sigf(s1[3]);
                c1 = fg * c1 + ig * gg;
                h1v = og * tanhfast(c1);
            }
            const float ig = sigf(s2[0]), fg = sigf(s2[1]);
            const float gg = tanhfast(s2[2]), og = sigf(s2[3]);
            c2 = fg * c2 + ig * gg;
            gstore2(&Pn[(size_t)j2 * Bb + bx], make_float2(h1v, og * tanhfast(c2)));
        }

        gbar(flags, wgid, tid, (u32)(t + 2));

        const float2* tp = Pc; Pc = Pn; Pn = (float2*)tp;
    }
    // final h2 = Pc[.].y

    // ---------- FC head: WG wgid handles batch wgid ----------
    float* hh  = fcb;
    float* a1s = fcb + Hh;
    float* a2s = fcb + Hh + 256;
    hh[tid] = Pc[(size_t)tid * Bb + wgid].y;   // cached, fresh post-fence
    __syncthreads();
    if (tid < 256) {
        float acc = fc1_b[tid];
        const float* wr = fc1_W + (size_t)tid * Hh;
        for (int i = 0; i < Hh; ++i) acc += wr[i] * hh[i];
        a1s[tid] = fmaxf(acc, 0.0f);
    }
    __syncthreads();
    if (tid < 128) {
        float acc = fc2_b[tid];
        const float* wr = fc2_W + (size_t)tid * 256;
        for (int i = 0; i < 256; ++i) acc += wr[i] * a1s[i];
        a2s[tid] = fmaxf(acc, 0.0f);
    }
    __syncthreads();
    if (tid == 0) {
        float acc = fc3_b[0];
        for (int i = 0; i < 128; ++i) acc += fc3_W[i] * a2s[i];
        out[wgid] = acc;
    }
}

extern "C" void kernel_launch(void* const* d_in, const int* in_sizes, int n_in,
                              void* d_out, int out_size, void* d_ws, size_t ws_size,
                              hipStream_t stream)
{
    (void)in_sizes; (void)n_in; (void)out_size; (void)ws_size;

    const float* input = (const float*)d_in[0];
    const float* l1_Wx = (const float*)d_in[1];
    const float* l1_bx = (const float*)d_in[2];
    const float* l1_Wh = (const float*)d_in[3];
    const float* l1_bh = (const float*)d_in[4];
    const float* l2_Wx = (const float*)d_in[5];
    const float* l2_bx = (const float*)d_in[6];
    const float* l2_Wh = (const float*)d_in[7];
    const float* l2_bh = (const float*)d_in[8];
    const float* fc1_W = (const float*)d_in[9];
    const float* fc1_b = (const float*)d_in[10];
    const float* fc2_W = (const float*)d_in[11];
    const float* fc2_b = (const float*)d_in[12];
    const float* fc3_W = (const float*)d_in[13];
    const float* fc3_b = (const float*)d_in[14];
    float* out = (float*)d_out;
    float* ws  = (float*)d_ws;

    void* args[] = {
        &input,
        &l1_Wx, &l1_bx, &l1_Wh, &l1_bh,
        &l2_Wx, &l2_bx, &l2_Wh, &l2_bh,
        &fc1_W, &fc1_b, &fc2_W, &fc2_b, &fc3_W, &fc3_b,
        &out, &ws
    };
    hipLaunchCooperativeKernel((void*)lstm_fused, dim3(NWG), dim3(NTHR), args, 0, stream);
}

// Round 14
// 32848.749 us; speedup vs baseline: 1.2431x; 1.2431x over previous
//
#include <hip/hip_runtime.h>
#include <hip/hip_cooperative_groups.h>

namespace cg = cooperative_groups;

#define Bb   256   // batch
#define Tt   512   // time steps
#define INx  19    // input features
#define Hh   512   // hidden
#define NWG  256   // wg owns units {2w, 2w+1}, all 256 batches (r7 geometry)
#define NTHR 512   // 8 waves: (su 0..1) x (bh 0..3); lane = (kq 0..3) x (bg 0..15)

typedef unsigned int u32;

__device__ __forceinline__ float sigf(float x) { return 1.0f / (1.0f + __expf(-x)); }
__device__ __forceinline__ float tanhfast(float x) {
    float e = __expf(2.0f * x);
    return 1.0f - 2.0f / (e + 1.0f);
}

// h stores: 4B agent-scope -> LLC-visible once vmcnt drains (r7-proven protocol)
__device__ __forceinline__ void gstore1(float* p, float v) {
    __hip_atomic_store(p, v, __ATOMIC_RELAXED, __HIP_MEMORY_SCOPE_AGENT);
}
__device__ __forceinline__ u32 gpoll(const u32* p) {
    return __hip_atomic_load(p, __ATOMIC_RELAXED, __HIP_MEMORY_SCOPE_AGENT);
}

// Weight LDS (r7-proven layout): [row 0..23][kq 0..3][132]; row = su*12 + m*4 + g
// (m: 0=l1_Wh, 1=l2_Wx, 2=l2_Wh). 528-stride keeps the 4 kq groups on disjoint banks.
#define WSTR 528

// One 4-gate sweep of one matrix over one h buffer (K-quarter kq, 4 batches bB..bB+3).
// wrow = wlds + (su*12 + m*4)*528 + kq*132. 2048 FMA, 128 ds_read_b128, 128 float4 loads.
__device__ __forceinline__ void sweep4(const float* __restrict__ hbuf,
                                       const float* __restrict__ wrow,
                                       int kq, int bB, float (&acc)[4][4]) {
    const float4* hp = reinterpret_cast<const float4*>(hbuf + (size_t)(kq * 128) * Bb) + (bB >> 2);
    float4 Hc[4], Hn[4];
    #pragma unroll
    for (int kk = 0; kk < 4; ++kk) Hc[kk] = hp[(size_t)kk * 64];
    #pragma unroll 1
    for (int c = 0; c < 32; ++c) {
        if (c < 31) {
            #pragma unroll
            for (int kk = 0; kk < 4; ++kk) Hn[kk] = hp[(size_t)((c + 1) * 4 + kk) * 64];
        }
        const float* wk = wrow + c * 4;
        #pragma unroll
        for (int g = 0; g < 4; ++g) {
            const float4 w = *reinterpret_cast<const float4*>(wk + g * WSTR);
            acc[g][0] += Hc[0].x * w.x + Hc[1].x * w.y + Hc[2].x * w.z + Hc[3].x * w.w;
            acc[g][1] += Hc[0].y * w.x + Hc[1].y * w.y + Hc[2].y * w.z + Hc[3].y * w.w;
            acc[g][2] += Hc[0].z * w.x + Hc[1].z * w.y + Hc[2].z * w.z + Hc[3].z * w.w;
            acc[g][3] += Hc[0].w * w.x + Hc[1].w * w.y + Hc[2].w * w.z + Hc[3].w * w.w;
        }
        #pragma unroll
        for (int kk = 0; kk < 4; ++kk) Hc[kk] = Hn[kk];
    }
}

__device__ __forceinline__ void butterfly(float (&a)[4][4]) {
    #pragma unroll
    for (int g = 0; g < 4; ++g)
        #pragma unroll
        for (int b = 0; b < 4; ++b) {
            float v = a[g][b];
            v += __shfl_xor(v, 16, 64);
            v += __shfl_xor(v, 32, 64);
            a[g][b] = v;
        }
}

__global__ void __launch_bounds__(NTHR, 2)
lstm_fused(const float* __restrict__ input,
           const float* __restrict__ l1_Wx, const float* __restrict__ l1_bx,
           const float* __restrict__ l1_Wh, const float* __restrict__ l1_bh,
           const float* __restrict__ l2_Wx, const float* __restrict__ l2_bx,
           const float* __restrict__ l2_Wh, const float* __restrict__ l2_bh,
           const float* __restrict__ fc1_W, const float* __restrict__ fc1_b,
           const float* __restrict__ fc2_W, const float* __restrict__ fc2_b,
           const float* __restrict__ fc3_W, const float* __restrict__ fc3_b,
           float* __restrict__ out, float* __restrict__ ws)
{
    __shared__ float wlds[24 * WSTR];        // 50.7 KB weights (fence-immune)
    __shared__ float wx1l[8 * 20];           // l1_Wx rows (2u x 4g), pad 20
    __shared__ float fcb[Hh + 256 + 128];    // FC head scratch

    cg::grid_group grid = cg::this_grid();
    const int wgid = blockIdx.x;
    const int jb = wgid * 2;
    const int tid = threadIdx.x;
    const int wid = tid >> 6, lane = tid & 63;
    const int su = wid & 1;              // unit select
    const int bh = wid >> 1;             // batch block (0..3)
    const int kq = lane >> 4;            // K quarter
    const int bg = lane & 15;
    const int bB = bh * 64 + bg * 4;     // first of this lane's 4 batches
    const int j  = jb + su;              // owned unit

    // ws: 3x h1 + 3x h2 (512 KB each, triple-buffered for the skew) + 2 flag arrays
    float* h1b[3]; float* h2b[3];
    #pragma unroll
    for (int i = 0; i < 3; ++i) {
        h1b[i] = ws + (size_t)i * Hh * Bb;
        h2b[i] = ws + (size_t)(3 + i) * Hh * Bb;
    }
    u32* flags  = (u32*)(ws + (size_t)6 * Hh * Bb);
    u32* flagsB = flags + NWG;

    if (tid == 0) {
        __hip_atomic_store(&flags[wgid], 0u, __ATOMIC_RELAXED, __HIP_MEMORY_SCOPE_AGENT);
        __hip_atomic_store(&flagsB[wgid], 0u, __ATOMIC_RELAXED, __HIP_MEMORY_SCOPE_AGENT);
    }
    grid.sync();   // fences flag resets; the only runtime cg sync

    // ---- stage weights into LDS (r7-proven) ----
    for (int idx = tid; idx < 24 * Hh; idx += NTHR) {
        const int row = idx >> 9, k = idx & 511;
        const int sru = row >= 12 ? 1 : 0;
        const int rr = row - sru * 12;
        const int m = rr >> 2, g = rr & 3;
        const float* src = (m == 0) ? l1_Wh : (m == 1) ? l2_Wx : l2_Wh;
        wlds[row * WSTR + (k >> 7) * 132 + (k & 127)] =
            src[(size_t)(g * Hh + jb + sru) * Hh + k];
    }
    if (tid < 8 * INx) {
        const int r = tid / INx, i = tid - r * INx;
        const int sru = r >> 2, g = r & 3;
        wx1l[r * 20 + i] = l1_Wx[(size_t)(g * Hh + jb + sru) * INx + i];
    }
    float b1r[4], b2r[4];
    #pragma unroll
    for (int g = 0; g < 4; ++g) {
        const int row = g * Hh + j;
        b1r[g] = l1_bx[row] + l1_bh[row];
        b2r[g] = l2_bx[row] + l2_bh[row];
    }
    __syncthreads();

    const float* wW1h = wlds + (su * 12 + 0) * WSTR + kq * 132;
    const float* wW2x = wlds + (su * 12 + 4) * WSTR + kq * 132;
    const float* wW2h = wlds + (su * 12 + 8) * WSTR + kq * 132;

    // ---- prologue: h1[0] from x[0] into h1b[0]; release flags=1 ----
    float c1[4] = {0.f, 0.f, 0.f, 0.f}, c2[4] = {0.f, 0.f, 0.f, 0.f};
    if (kq == 0) {
        #pragma unroll
        for (int b = 0; b < 4; ++b) {
            const float* xr = input + (size_t)(bB + b) * Tt * INx;
            float s[4];
            #pragma unroll
            for (int g = 0; g < 4; ++g) {
                float acc = b1r[g];
                #pragma unroll
                for (int i = 0; i < INx; ++i) acc += xr[i] * wx1l[(su * 4 + g) * 20 + i];
                s[g] = acc;
            }
            c1[b] = sigf(s[0]) * tanhfast(s[2]);
            gstore1(&h1b[0][(size_t)j * Bb + bB + b], sigf(s[3]) * tanhfast(c1[b]));
        }
    }
    __syncthreads();
    if (tid == 0)
        __hip_atomic_store(&flags[wgid], 1u, __ATOMIC_RELEASE, __HIP_MEMORY_SCOPE_AGENT);

    // ---- skewed phases: phase t computes h2[t-1] (pre-barrier) and h1[t+1] (post) ----
    for (int t = 0; t <= Tt; ++t) {
        const bool dL2  = (t >= 1);
        const bool dL2h = (t >= 2);
        const bool dL1  = (t < Tt - 1);
        const float* h1m = h1b[(t + 2) % 3];   // h1[t-1] (warm: read post-fence last phase)
        const float* h1c = h1b[t % 3];         // h1[t]   (cold, post-fence)
        float*       h1n = h1b[(t + 1) % 3];   // h1[t+1]
        const float* h2m = h2b[(t + 1) % 3];   // h2[t-2]
        float*       h2n = h2b[(t + 2) % 3];   // h2[t-1]

        // P0: cheap early-flag wait for h2[t-2] (set mid-phase t-1 -> ~no wait)
        if (dL2h) {
            if (tid < NWG)
                while (gpoll(&flagsB[tid]) < (u32)t) __builtin_amdgcn_s_sleep(2);
            __syncthreads();
        }

        // P1+P2: pre-barrier layer-2 work (2/3 of FMA), h2[t-1] finish+store
        if (dL2) {
            float a2[4][4];
            #pragma unroll
            for (int g = 0; g < 4; ++g)
                #pragma unroll
                for (int b = 0; b < 4; ++b) a2[g][b] = 0.f;
            sweep4(h1m, wW2x, kq, bB, a2);          // warm L2 hits
            if (dL2h) sweep4(h2m, wW2h, kq, bB, a2); // cold, overlapped here
            butterfly(a2);
            if (kq == 0) {
                #pragma unroll
                for (int b = 0; b < 4; ++b) {
                    const float ig = sigf(a2[0][b] + b2r[0]);
                    const float fg = sigf(a2[1][b] + b2r[1]);
                    const float gg = tanhfast(a2[2][b] + b2r[2]);
                    const float og = sigf(a2[3][b] + b2r[3]);
                    c2[b] = fg * c2[b] + ig * gg;
                    gstore1(&h2n[(size_t)j * Bb + bB + b], og * tanhfast(c2[b]));
                }
            }
        }
        // P3: early flag for h2[t-1]
        __syncthreads();   // drains h2 stores of all waves
        if (tid == 0)
            __hip_atomic_store(&flagsB[wgid], (u32)(t + 1), __ATOMIC_RELEASE, __HIP_MEMORY_SCOPE_AGENT);

        // P4: main barrier (h1[t] ready) + the one acquire fence
        if (tid < NWG)
            while (gpoll(&flags[tid]) < (u32)(t + 1)) __builtin_amdgcn_s_sleep(2);
        __syncthreads();
        __builtin_amdgcn_fence(__ATOMIC_ACQUIRE, "agent");   // L1/L2 inv

        // P5: post-barrier layer-1 work (1/3 of FMA): h1[t+1]
        if (dL1) {
            float a1[4][4];
            #pragma unroll
            for (int g = 0; g < 4; ++g)
                #pragma unroll
                for (int b = 0; b < 4; ++b) a1[g][b] = 0.f;
            sweep4(h1c, wW1h, kq, bB, a1);           // cold 512 KB (halved)
            butterfly(a1);
            if (kq == 0) {
                #pragma unroll
                for (int b = 0; b < 4; ++b) {
                    const float* xr = input + ((size_t)(bB + b) * Tt + t + 1) * INx;
                    float s[4];
                    #pragma unroll
                    for (int g = 0; g < 4; ++g) {
                        float acc = a1[g][b] + b1r[g];
                        #pragma unroll
                        for (int i = 0; i < INx; ++i) acc += xr[i] * wx1l[(su * 4 + g) * 20 + i];
                        s[g] = acc;
                    }
                    const float ig = sigf(s[0]), fg = sigf(s[1]);
                    const float gg = tanhfast(s[2]), og = sigf(s[3]);
                    c1[b] = fg * c1[b] + ig * gg;
                    gstore1(&h1n[(size_t)j * Bb + bB + b], og * tanhfast(c1[b]));
                }
            }
        }
        // P6: main flag release (h1[t+1] and h2[t-1] both stored+drained)
        __syncthreads();
        if (tid == 0)
            __hip_atomic_store(&flags[wgid], (u32)(t + 2), __ATOMIC_RELEASE, __HIP_MEMORY_SCOPE_AGENT);
    }

    // ---- final join: all phases done -> h2[511] globally visible ----
    if (tid < NWG)
        while (gpoll(&flags[tid]) < (u32)(Tt + 2)) __builtin_amdgcn_s_sleep(2);
    __syncthreads();
    __builtin_amdgcn_fence(__ATOMIC_ACQUIRE, "agent");

    // ---------- FC head: WG wgid handles batch wgid ----------
    const float* h2f = h2b[(Tt - 1) % 3];    // h2[511]
    float* hh  = fcb;
    float* a1s = fcb + Hh;
    float* a2s = fcb + Hh + 256;
    hh[tid] = h2f[(size_t)tid * Bb + wgid];
    __syncthreads();
    if (tid < 256) {
        float acc = fc1_b[tid];
        const float* wr = fc1_W + (size_t)tid * Hh;
        for (int i = 0; i < Hh; ++i) acc += wr[i] * hh[i];
        a1s[tid] = fmaxf(acc, 0.0f);
    }
    __syncthreads();
    if (tid < 128) {
        float acc = fc2_b[tid];
        const float* wr = fc2_W + (size_t)tid * 256;
        for (int i = 0; i < 256; ++i) acc += wr[i] * a1s[i];
        a2s[tid] = fmaxf(acc, 0.0f);
    }
    __syncthreads();
    if (tid == 0) {
        float acc = fc3_b[0];
        for (int i = 0; i < 128; ++i) acc += fc3_W[i] * a2s[i];
        out[wgid] = acc;
    }
}

extern "C" void kernel_launch(void* const* d_in, const int* in_sizes, int n_in,
                              void* d_out, int out_size, void* d_ws, size_t ws_size,
                              hipStream_t stream)
{
    (void)in_sizes; (void)n_in; (void)out_size; (void)ws_size;

    const float* input = (const float*)d_in[0];
    const float* l1_Wx = (const float*)d_in[1];
    const float* l1_bx = (const float*)d_in[2];
    const float* l1_Wh = (const float*)d_in[3];
    const float* l1_bh = (const float*)d_in[4];
    const float* l2_Wx = (const float*)d_in[5];
    const float* l2_bx = (const float*)d_in[6];
    const float* l2_Wh = (const float*)d_in[7];
    const float* l2_bh = (const float*)d_in[8];
    const float* fc1_W = (const float*)d_in[9];
    const float* fc1_b = (const float*)d_in[10];
    const float* fc2_W = (const float*)d_in[11];
    const float* fc2_b = (const float*)d_in[12];
    const float* fc3_W = (const float*)d_in[13];
    const float* fc3_b = (const float*)d_in[14];
    float* out = (float*)d_out;
    float* ws  = (float*)d_ws;

    void* args[] = {
        &input,
        &l1_Wx, &l1_bx, &l1_Wh, &l1_bh,
        &l2_Wx, &l2_bx, &l2_Wh, &l2_bh,
        &fc1_W, &fc1_b, &fc2_W, &fc2_b, &fc3_W, &fc3_b,
        &out, &ws
    };
    hipLaunchCooperativeKernel((void*)lstm_fused, dim3(NWG), dim3(NTHR), args, 0, stream);
}

// Round 15
// 28468.015 us; speedup vs baseline: 1.4343x; 1.1539x over previous
//
#include <hip/hip_runtime.h>
#include <hip/hip_cooperative_groups.h>

namespace cg = cooperative_groups;

#define Bb   256   // batch
#define Tt   512   // time steps
#define INx  19    // input features
#define Hh   512   // hidden
#define NWG  256   // (unit-group 0..127 of 4 units) x (batch-half 0..1 of 128)
#define NTHR 512   // 8 waves = (su 0..3) x (bh 0..1); lane = (kq 0..3) x (bg 0..15)

#define WROWS 48                      // 4 units x 12 rows
#define WSTR  528                     // r7-proven bank-safe stride
#define WLDS_FLOATS (WROWS * WSTR)    // 101376 B
#define WX1_FLOATS  (16 * 20)
#define FCB_FLOATS  (Hh + 256 + 128)
#define SMEM_FLOATS (WLDS_FLOATS + WX1_FLOATS + FCB_FLOATS)
#define SMEM_BYTES  (SMEM_FLOATS * 4)

typedef unsigned int u32;
typedef unsigned long long u64;

__device__ __forceinline__ float sigf(float x) { return 1.0f / (1.0f + __expf(-x)); }
__device__ __forceinline__ float tanhfast(float x) {
    float e = __expf(2.0f * x);
    return 1.0f - 2.0f / (e + 1.0f);
}

union pcast { u64 u; float2 f; };
// h pair stores: 8B agent-scope -> LLC-visible once vmcnt drains (r9-proven)
__device__ __forceinline__ void gstore2(float2* p, float2 v) {
    pcast c; c.f = v;
    __hip_atomic_store((u64*)p, c.u, __ATOMIC_RELAXED, __HIP_MEMORY_SCOPE_AGENT);
}

// r9's exact barrier: drain, release flag, poll 256 flags, acquire fence.
__device__ __forceinline__ void gbar(u32* flags, int wgid, int tid, u32 phase) {
    __syncthreads();
    if (tid == 0)
        __hip_atomic_store(&flags[wgid], phase, __ATOMIC_RELEASE, __HIP_MEMORY_SCOPE_AGENT);
    if (tid < NWG) {
        const u32* fp = &flags[tid];
        while (__hip_atomic_load(fp, __ATOMIC_RELAXED, __HIP_MEMORY_SCOPE_AGENT) < phase)
            __builtin_amdgcn_s_sleep(2);
    }
    __syncthreads();
    __builtin_amdgcn_fence(__ATOMIC_ACQUIRE, "agent");   // L1/L2 inv -> fresh h
}

// load chunk c: 4 consecutive k's x 4 batches of (h1,h2) pairs = 8 float4
__device__ __forceinline__ void ldh(const float4* __restrict__ hp, int c,
                                    float4 (&A)[4], float4 (&B)[4]) {
    #pragma unroll
    for (int kk = 0; kk < 4; ++kk) {
        A[kk] = hp[(size_t)(c * 4 + kk) * 128];
        B[kk] = hp[(size_t)(c * 4 + kk) * 128 + 1];
    }
}

// 192 FMA per chunk: 12 weight rows (LDS broadcast) x 4 k x 4 batches.
// A[kk]=(h1_b0,h2_b0,h1_b1,h2_b1), B[kk]=(h1_b2,h2_b2,h1_b3,h2_b3).
// a2 merges W2x·h1 + W2h·h2 into one accumulator (r9/r13-proven).
__device__ __forceinline__ void fmac(const float4 (&A)[4], const float4 (&B)[4],
                                     const float* __restrict__ wk,
                                     float (&a1)[4][4], float (&a2)[4][4]) {
    #pragma unroll
    for (int g = 0; g < 4; ++g) {
        const float4 w1 = *reinterpret_cast<const float4*>(wk + (0 + g) * WSTR);
        const float4 w2 = *reinterpret_cast<const float4*>(wk + (4 + g) * WSTR);
        const float4 w3 = *reinterpret_cast<const float4*>(wk + (8 + g) * WSTR);
        a1[g][0] += A[0].x*w1.x + A[1].x*w1.y + A[2].x*w1.z + A[3].x*w1.w;
        a1[g][1] += A[0].z*w1.x + A[1].z*w1.y + A[2].z*w1.z + A[3].z*w1.w;
        a1[g][2] += B[0].x*w1.x + B[1].x*w1.y + B[2].x*w1.z + B[3].x*w1.w;
        a1[g][3] += B[0].z*w1.x + B[1].z*w1.y + B[2].z*w1.z + B[3].z*w1.w;
        a2[g][0] += A[0].x*w2.x + A[1].x*w2.y + A[2].x*w2.z + A[3].x*w2.w
                  + A[0].y*w3.x + A[1].y*w3.y + A[2].y*w3.z + A[3].y*w3.w;
        a2[g][1] += A[0].z*w2.x + A[1].z*w2.y + A[2].z*w2.z + A[3].z*w2.w
                  + A[0].w*w3.x + A[1].w*w3.y + A[2].w*w3.z + A[3].w*w3.w;
        a2[g][2] += B[0].x*w2.x + B[1].x*w2.y + B[2].x*w2.z + B[3].x*w2.w
                  + B[0].y*w3.x + B[1].y*w3.y + B[2].y*w3.z + B[3].y*w3.w;
        a2[g][3] += B[0].z*w2.x + B[1].z*w2.y + B[2].z*w2.z + B[3].z*w2.w
                  + B[0].w*w3.x + B[1].w*w3.y + B[2].w*w3.z + B[3].w*w3.w;
    }
}

__global__ void __launch_bounds__(NTHR, 2)
lstm_fused(const float* __restrict__ input,
           const float* __restrict__ l1_Wx, const float* __restrict__ l1_bx,
           const float* __restrict__ l1_Wh, const float* __restrict__ l1_bh,
           const float* __restrict__ l2_Wx, const float* __restrict__ l2_bx,
           const float* __restrict__ l2_Wh, const float* __restrict__ l2_bh,
           const float* __restrict__ fc1_W, const float* __restrict__ fc1_b,
           const float* __restrict__ fc2_W, const float* __restrict__ fc2_b,
           const float* __restrict__ fc3_W, const float* __restrict__ fc3_b,
           float* __restrict__ out, float* __restrict__ ws)
{
    extern __shared__ float smem[];
    float* wlds = smem;                      // [48 rows][528] fence-immune weights
    float* wx1l = smem + WLDS_FLOATS;        // [4u][4g][20]
    float* fcb  = wx1l + WX1_FLOATS;

    cg::grid_group grid = cg::this_grid();
    const int wgid = blockIdx.x;
    const int ug = wgid >> 1;        // unit-group
    const int bs = wgid & 1;         // batch-half
    const int jb = ug * 4;           // first owned unit
    const int tid = threadIdx.x;

    const int wid = __builtin_amdgcn_readfirstlane(tid >> 6);
    const int su = wid & 3;          // unit within group (wave-uniform)
    const int bh = wid >> 2;         // batch block of 64 (wave-uniform)
    const int lane = tid & 63;
    const int kq = lane >> 4;        // K quarter
    const int bg = lane & 15;
    const int bB = bs * 128 + bh * 64 + bg * 4;   // first of this lane's 4 batches
    const int j  = jb + su;          // owned unit

    float2* PA = (float2*)ws;        // P[j][b] = (h1[t], h2[t-1])
    float2* PB = PA + (size_t)Hh * Bb;
    u32* flags = (u32*)(PB + (size_t)Hh * Bb);

    if (tid == 0)
        __hip_atomic_store(&flags[wgid], 0u, __ATOMIC_RELAXED, __HIP_MEMORY_SCOPE_AGENT);
    grid.sync();   // fences flag resets; the only runtime cg sync

    // ---- stage 4 units x 12 rows of weights into LDS (once; fence-immune) ----
    for (int idx = tid; idx < WROWS * Hh; idx += NTHR) {
        const int row = idx >> 9, k = idx & 511;
        const int u = row / 12, rr = row - u * 12;
        const int m = rr >> 2, g = rr & 3;
        const float* src = (m == 0) ? l1_Wh : (m == 1) ? l2_Wx : l2_Wh;
        wlds[row * WSTR + (k >> 7) * 132 + (k & 127)] =
            src[(size_t)(g * Hh + jb + u) * Hh + k];
    }
    if (tid < 16 * INx) {
        const int r = tid / INx, i = tid - r * INx;
        const int u = r >> 2, g = r & 3;
        wx1l[r * 20 + i] = l1_Wx[(size_t)(g * Hh + jb + u) * INx + i];
    }
    float b1r[4], b2r[4];
    #pragma unroll
    for (int g = 0; g < 4; ++g) {
        const int row = g * Hh + j;
        b1r[g] = l1_bx[row] + l1_bh[row];
        b2r[g] = l2_bx[row] + l2_bh[row];
    }
    __syncthreads();

    const float* wlane = wlds + (su * 12) * WSTR + kq * 132;

    // ---- prologue (kq==0 lanes): P = (h1[0], h2[-1]=0) for 4 batches ----
    float c1[4] = {0.f, 0.f, 0.f, 0.f}, c2[4] = {0.f, 0.f, 0.f, 0.f};
    if (kq == 0) {
        #pragma unroll
        for (int b = 0; b < 4; ++b) {
            const float* xr = input + (size_t)(bB + b) * Tt * INx;
            float s[4];
            #pragma unroll
            for (int g = 0; g < 4; ++g) {
                float acc = b1r[g];
                #pragma unroll
                for (int i = 0; i < INx; ++i) acc += xr[i] * wx1l[(su * 4 + g) * 20 + i];
                s[g] = acc;
            }
            c1[b] = sigf(s[0]) * tanhfast(s[2]);       // f*0 + i*g
            gstore2(&PA[(size_t)j * Bb + bB + b],
                    make_float2(sigf(s[3]) * tanhfast(c1[b]), 0.f));
        }
    }
    gbar(flags, wgid, tid, 1u);

    const float2* Pc = PA; float2* Pn = PB;

    for (int t = 0; t < Tt; ++t) {
        const bool doL1 = (t < Tt - 1);

        float a1[4][4], a2[4][4];
        #pragma unroll
        for (int g = 0; g < 4; ++g)
            #pragma unroll
            for (int b = 0; b < 4; ++b) { a1[g][b] = 0.f; a2[g][b] = 0.f; }

        // lane float4 base: f4 idx = k*128 + bB/2, k = kq*128 + ...
        const float4* hp = (const float4*)Pc + (size_t)(kq * 128) * 128 + (bB >> 1);

        // r7-proven double-buffered pipeline over 32 chunks of 4 k's
        float4 Ac[4], Bc[4], An[4], Bn[4];
        ldh(hp, 0, Ac, Bc);
        #pragma unroll 1
        for (int c = 0; c < 32; c += 2) {
            ldh(hp, c + 1, An, Bn);
            fmac(Ac, Bc, wlane + (c    ) * 4, a1, a2);
            if (c < 30) ldh(hp, c + 2, Ac, Bc);
            fmac(An, Bn, wlane + (c + 1) * 4, a1, a2);
        }

        // ---- butterfly K-reduce over the 4 kq groups (lane bits 4,5) ----
        #pragma unroll
        for (int g = 0; g < 4; ++g) {
            #pragma unroll
            for (int b = 0; b < 4; ++b) {
                float v = a1[g][b]; v += __shfl_xor(v, 16, 64); v += __shfl_xor(v, 32, 64); a1[g][b] = v;
                float w = a2[g][b]; w += __shfl_xor(w, 16, 64); w += __shfl_xor(w, 32, 64); a2[g][b] = w;
            }
        }

        // ---- finish (kq==0 lanes: unit j, 4 batches), store pairs ----
        if (kq == 0) {
            #pragma unroll
            for (int b = 0; b < 4; ++b) {
                const int bb = bB + b;
                float h1v = 0.f;
                if (doL1) {
                    const float* xr = input + ((size_t)bb * Tt + t + 1) * INx;
                    float s1[4];
                    #pragma unroll
                    for (int g = 0; g < 4; ++g) {
                        float acc = a1[g][b] + b1r[g];
                        #pragma unroll
                        for (int i = 0; i < INx; ++i) acc += xr[i] * wx1l[(su * 4 + g) * 20 + i];
                        s1[g] = acc;
                    }
                    const float ig = sigf(s1[0]), fg = sigf(s1[1]);
                    const float gg = tanhfast(s1[2]), og = sigf(s1[3]);
                    c1[b] = fg * c1[b] + ig * gg;
                    h1v = og * tanhfast(c1[b]);
                }
                const float ig = sigf(a2[0][b] + b2r[0]);
                const float fg = sigf(a2[1][b] + b2r[1]);
                const float gg = tanhfast(a2[2][b] + b2r[2]);
                const float og = sigf(a2[3][b] + b2r[3]);
                c2[b] = fg * c2[b] + ig * gg;
                gstore2(&Pn[(size_t)j * Bb + bb], make_float2(h1v, og * tanhfast(c2[b])));
            }
        }

        gbar(flags, wgid, tid, (u32)(t + 2));

        const float2* tp = Pc; Pc = Pn; Pn = (float2*)tp;
    }
    // final h2 = Pc[.].y

    // ---------- FC head: WG wgid handles batch wgid ----------
    float* hh  = fcb;
    float* a1s = fcb + Hh;
    float* a2s = fcb + Hh + 256;
    hh[tid] = Pc[(size_t)tid * Bb + wgid].y;   // cached, fresh post-fence
    __syncthreads();
    if (tid < 256) {
        float acc = fc1_b[tid];
        const float* wr = fc1_W + (size_t)tid * Hh;
        for (int i = 0; i < Hh; ++i) acc += wr[i] * hh[i];
        a1s[tid] = fmaxf(acc, 0.0f);
    }
    __syncthreads();
    if (tid < 128) {
        float acc = fc2_b[tid];
        const float* wr = fc2_W + (size_t)tid * 256;
        for (int i = 0; i < 256; ++i) acc += wr[i] * a1s[i];
        a2s[tid] = fmaxf(acc, 0.0f);
    }
    __syncthreads();
    if (tid == 0) {
        float acc = fc3_b[0];
        for (int i = 0; i < 128; ++i) acc += fc3_W[i] * a2s[i];
        out[wgid] = acc;
    }
}

extern "C" void kernel_launch(void* const* d_in, const int* in_sizes, int n_in,
                              void* d_out, int out_size, void* d_ws, size_t ws_size,
                              hipStream_t stream)
{
    (void)in_sizes; (void)n_in; (void)out_size; (void)ws_size;

    const float* input = (const float*)d_in[0];
    const float* l1_Wx = (const float*)d_in[1];
    const float* l1_bx = (const float*)d_in[2];
    const float* l1_Wh = (const float*)d_in[3];
    const float* l1_bh = (const float*)d_in[4];
    const float* l2_Wx = (const float*)d_in[5];
    const float* l2_bx = (const float*)d_in[6];
    const float* l2_Wh = (const float*)d_in[7];
    const float* l2_bh = (const float*)d_in[8];
    const float* fc1_W = (const float*)d_in[9];
    const float* fc1_b = (const float*)d_in[10];
    const float* fc2_W = (const float*)d_in[11];
    const float* fc2_b = (const float*)d_in[12];
    const float* fc3_W = (const float*)d_in[13];
    const float* fc3_b = (const float*)d_in[14];
    float* out = (float*)d_out;
    float* ws  = (float*)d_ws;

    hipFuncSetAttribute((const void*)lstm_fused,
                        hipFuncAttributeMaxDynamicSharedMemorySize, SMEM_BYTES);

    void* args[] = {
        &input,
        &l1_Wx, &l1_bx, &l1_Wh, &l1_bh,
        &l2_Wx, &l2_bx, &l2_Wh, &l2_bh,
        &fc1_W, &fc1_b, &fc2_W, &fc2_b, &fc3_W, &fc3_b,
        &out, &ws
    };
    hipLaunchCooperativeKernel((void*)lstm_fused, dim3(NWG), dim3(NTHR), args,
                               SMEM_BYTES, stream);
}